// Round 14
// baseline (245.307 us; speedup 1.0000x reference)
//
#include <hip/hip_runtime.h>
#include <hip/hip_bf16.h>
#include <stdint.h>

#define B_N 8
#define T_N 2048
#define FDIM_N 512
#define H_N 8
#define DK_N 64

typedef float f32x4 __attribute__((ext_vector_type(4)));
typedef float float4v __attribute__((ext_vector_type(4)));
typedef __bf16 bf16x8 __attribute__((ext_vector_type(8)));
typedef unsigned short ushort8v __attribute__((ext_vector_type(8)));
typedef unsigned int uint2v __attribute__((ext_vector_type(2)));
typedef unsigned int uint4v __attribute__((ext_vector_type(4)));

#if __has_builtin(__builtin_amdgcn_exp2f)
#define EXP2F(x) __builtin_amdgcn_exp2f(x)
#else
#define EXP2F(x) exp2f(x)
#endif

static __device__ __forceinline__ unsigned short f2bf(float f) {
  unsigned int u = __builtin_bit_cast(unsigned int, f);
  u += 0x7fffu + ((u >> 16) & 1u);
  return (unsigned short)(u >> 16);
}

// v_cvt_pk_bf16_f32: lo -> bits[15:0], hi -> bits[31:16] (RNE)
static __device__ __forceinline__ unsigned cvtpk(float lo, float hi) {
  unsigned r;
  asm("v_cvt_pk_bf16_f32 %0, %1, %2" : "=v"(r) : "v"(lo), "v"(hi));
  return r;
}

static __device__ __forceinline__ void gld_lds16(const void* g, void* l) {
  __builtin_amdgcn_global_load_lds(
      (const __attribute__((address_space(1))) unsigned int*)g,
      (__attribute__((address_space(3))) unsigned int*)l, 16, 0, 0);
}

static __device__ __forceinline__ bf16x8 ld_bf8(const unsigned short* p) {
  return *reinterpret_cast<const bf16x8*>(p);
}

// elem-offset XOR swizzle for 64-elem bf16 rows (8-elem granules)
#define SWZ8(row, colE) ((colE) ^ (((row) & 7) << 3))

// combined softmax scale: 1/sqrt(64) * log2(e)  (exp2-domain softmax, no-max)
#define QSCALE 0.1803368801111244f

// ---------------- prep: mask pack + weight cvt + qkv input cvt [R12-proven] ---
__global__ __launch_bounds__(256) void prep_k(
    const int* __restrict__ m, const float* __restrict__ w0, const float* __restrict__ w1,
    const float* __restrict__ w2, const float* __restrict__ w3,
    const float* __restrict__ qin, const float* __restrict__ kin, const float* __restrict__ vin,
    unsigned short* __restrict__ wb, unsigned short* __restrict__ qb,
    unsigned short* __restrict__ kb, unsigned short* __restrict__ vb,
    unsigned long long* __restrict__ mbits) {
  const int bid = blockIdx.x;
  if (bid < 2048) {
    const size_t n = (size_t)B_N * T_N * T_N;
    const size_t stride = (size_t)2048 * 256;
    for (size_t i = (size_t)bid * 256 + threadIdx.x; i < n; i += stride) {
      unsigned long long bl = __ballot(m[i] != 0);
      if ((threadIdx.x & 63) == 0) mbits[i >> 6] = bl;
    }
  } else if (bid < 2560) {
    const int i = (bid - 2048) * 256 + threadIdx.x;  // [0, 131072)
    const int ws = i >> 15, o = i & 32767;
    const float* w = (ws == 0) ? w0 : (ws == 1) ? w1 : (ws == 2) ? w2 : w3;
    const float4v a = *reinterpret_cast<const float4v*>(w + (size_t)o * 8);
    const float4v b = *reinterpret_cast<const float4v*>(w + (size_t)o * 8 + 4);
    const ushort8v out = {f2bf(a.x), f2bf(a.y), f2bf(a.z), f2bf(a.w),
                          f2bf(b.x), f2bf(b.y), f2bf(b.z), f2bf(b.w)};
    *reinterpret_cast<ushort8v*>(wb + (size_t)i * 8) = out;
  } else {
    const unsigned total = 3u << 20;  // 3 x 2^20 ushort8-chunks
    const unsigned stride = 1536u * 256u;
    for (unsigned i = (bid - 2560) * 256 + threadIdx.x; i < total; i += stride) {
      const unsigned sel = i >> 20, off = i & 0xFFFFFu;
      const float* in = (sel == 0) ? qin : (sel == 1) ? kin : vin;
      unsigned short* out = (sel == 0) ? qb : (sel == 1) ? kb : vb;
      const float4v a = *reinterpret_cast<const float4v*>(in + (size_t)off * 8);
      const float4v b = *reinterpret_cast<const float4v*>(in + (size_t)off * 8 + 4);
      const ushort8v o = {f2bf(a.x), f2bf(a.y), f2bf(a.z), f2bf(a.w),
                          f2bf(b.x), f2bf(b.y), f2bf(b.z), f2bf(b.w)};
      *reinterpret_cast<ushort8v*>(out + (size_t)off * 8) = o;
    }
  }
}

// ---------------- single GEMM, all-bf16 m97 pattern [R12-proven] --------------
// MODE 0: q (QSCALE, layout0)  1: k (layout0)  2: vT (pi permute)  3: f32 out
template <int MODE>
__global__ __launch_bounds__(256, 3) void gemm_bt_k(const unsigned short* __restrict__ Ap,
                                                    const unsigned short* __restrict__ Wp,
                                                    const float* __restrict__ biasp,
                                                    void* __restrict__ Cp) {
  __shared__ unsigned short As[128 * 64];
  __shared__ unsigned short Bs[128 * 64];
  const int tid = threadIdx.x;
  const int lane = tid & 63, w = tid >> 6;
  const int lr = lane & 15, lg = lane >> 4;
  const int id = blockIdx.x;
  const int work = (id & 7) * 64 + (id >> 3);  // XCD swizzle over 512
  const int m0 = (work >> 2) * 128, n0 = (work & 3) * 128;
  const int wm = (w & 1) * 64, wn = (w >> 1) * 64;
  const int swz_rd = (lr & 7) << 3;

  f32x4 acc[4][4];
  const f32x4 z4 = {0.f, 0.f, 0.f, 0.f};
#pragma unroll
  for (int i = 0; i < 4; ++i)
#pragma unroll
    for (int j = 0; j < 4; ++j) acc[i][j] = z4;

  for (int k0 = 0; k0 < 512; k0 += 64) {
    __syncthreads();
#pragma unroll
    for (int i = 0; i < 4; ++i) {
      const int c = i * 256 + tid;
      const int row = c >> 3, ch = c & 7;
      const int sw = SWZ8(row, ch * 8);
      gld_lds16(Ap + (size_t)(m0 + row) * 512 + k0 + sw, &As[c * 8]);
      gld_lds16(Wp + (size_t)(n0 + row) * 512 + k0 + sw, &Bs[c * 8]);
    }
    __syncthreads();
    bf16x8 af[4][2], bw[4][2];
#pragma unroll
    for (int mt = 0; mt < 4; ++mt)
#pragma unroll
      for (int kk = 0; kk < 2; ++kk)
        af[mt][kk] = ld_bf8(&As[(wm + mt * 16 + lr) * 64 + ((kk * 32 + lg * 8) ^ swz_rd)]);
#pragma unroll
    for (int nt = 0; nt < 4; ++nt)
#pragma unroll
      for (int kk = 0; kk < 2; ++kk)
        bw[nt][kk] = ld_bf8(&Bs[(wn + nt * 16 + lr) * 64 + ((kk * 32 + lg * 8) ^ swz_rd)]);
#pragma unroll
    for (int kk = 0; kk < 2; ++kk)
#pragma unroll
      for (int mt = 0; mt < 4; ++mt)
#pragma unroll
        for (int nt = 0; nt < 4; ++nt)
          acc[mt][nt] =
              __builtin_amdgcn_mfma_f32_16x16x32_bf16(af[mt][kk], bw[nt][kk], acc[mt][nt], 0, 0, 0);
  }

#pragma unroll
  for (int nt = 0; nt < 4; ++nt) {
    const int n = n0 + wn + nt * 16 + lr;
    const float bias = biasp[n];
#pragma unroll
    for (int mt = 0; mt < 4; ++mt) {
#pragma unroll
      for (int j = 0; j < 4; ++j) {
        const int m = m0 + wm + mt * 16 + lg * 4 + j;
        float v = acc[mt][nt][j] + bias;
        const int bb = m >> 11, t = m & 2047;
        const int hh = n >> 6, d = n & 63;
        if constexpr (MODE == 0) {
          v *= QSCALE;  // fold 1/sqrt(dk)*log2e into q
          ((unsigned short*)Cp)[(((size_t)(bb * 8 + hh) * 2048 + t) << 6) + d] = f2bf(v);
        } else if constexpr (MODE == 1) {
          ((unsigned short*)Cp)[(((size_t)(bb * 8 + hh) * 2048 + t) << 6) + d] = f2bf(v);
        } else if constexpr (MODE == 2) {
          // pi: bits {0,1}->{0,1}, {2,3}->{3,4}, {4}->{2} within each 32-block
          const int tp = (t & ~31) | (((t >> 2) & 3) << 3) | (((t >> 4) & 1) << 2) | (t & 3);
          ((unsigned short*)Cp)[(((size_t)(bb * 8 + hh) * 64 + d) << 11) + tp] = f2bf(v);
        } else {
          ((float*)Cp)[(size_t)m * 512 + n] = v;
        }
      }
    }
  }
}

// ---------------- flash attention: 8 waves x 32 q-rows (2 chains), KVBLK=64 ----
// R13 skeleton (4-buffer, 1 barrier/2 tiles, hoisted pointers) + 2 independent
// 16-row chains per wave (qt=0/1): within-wave ILP fills dependency bubbles;
// K/V fragment LDS reads shared across both chains. QBLK=256, grid 512.
__global__ __launch_bounds__(512, 4) void attn_k(
    const unsigned short* __restrict__ qg, const unsigned short* __restrict__ kg,
    const unsigned short* __restrict__ vtg, const unsigned long long* __restrict__ mb,
    unsigned short* __restrict__ xg) {
  __shared__ unsigned short L[4 * 8192];  // 64 KB: 4 x {K 64x64, V^T 64x64}

  const int tid = threadIdx.x;
  const int lane = tid & 63, w = tid >> 6;  // w in [0,8)
  const int lr = lane & 15, lg = lane >> 4;
  const int swz_rd = (lr & 7) << 3;
  const int id = blockIdx.x;
  const int work = (id & 7) * 64 + (id >> 3);  // XCD swizzle over 512
  const int bh = work >> 3, qt0 = work & 7;
  const int b = bh >> 3, h = bh & 7;
  const int q0 = qt0 * 256;

  // Q B-frags: wave owns rows q0 + w*32 + qt*16 + lr, qt in {0,1}
  bf16x8 aq[2][2];
#pragma unroll
  for (int qt = 0; qt < 2; ++qt)
#pragma unroll
    for (int kk = 0; kk < 2; ++kk)
      aq[qt][kk] =
          ld_bf8(qg + ((size_t)bh * T_N + q0 + w * 32 + qt * 16 + lr) * DK_N + kk * 32 + lg * 8);

  // hoisted LDS read pointers (buffer/K-vs-V select folds into immediates)
  const unsigned short* rp[8];
#pragma unroll
  for (int st = 0; st < 4; ++st) {
    rp[2 * st + 0] = &L[(st * 16 + lr) * 64 + ((lg * 8) ^ swz_rd)];
    rp[2 * st + 1] = &L[(st * 16 + lr) * 64 + ((32 + lg * 8) ^ swz_rd)];
  }

  const int krow = tid >> 3, kch = tid & 7;
  const unsigned short* kp =
      kg + (size_t)bh * (T_N * DK_N) + krow * 64 + SWZ8(krow, kch * 8);
  const unsigned short* vp =
      vtg + ((size_t)bh * DK_N + krow) * T_N + SWZ8(krow, kch * 8);
  const unsigned long long* mpA = mb + ((size_t)b * T_N + q0 + w * 32 + lr) * (T_N / 64);
  const unsigned long long* mpB = mpA + 16 * (T_N / 64);

  f32x4 OT[2][4];
  float rsacc[2] = {0.f, 0.f};
  const f32x4 z4 = {0.f, 0.f, 0.f, 0.f};
#pragma unroll
  for (int qt = 0; qt < 2; ++qt)
#pragma unroll
    for (int dt = 0; dt < 4; ++dt) OT[qt][dt] = z4;

  f32x4 ST[2][4];
  bf16x8 pfrag[2][2];
  unsigned long long mA0, mA1, mB0, mB1;

#define STG(B_)                                       \
  {                                                   \
    gld_lds16(kp, &L[(B_) * 8192 + tid * 8]);         \
    gld_lds16(vp, &L[(B_) * 8192 + 4096 + tid * 8]);  \
    kp += 4096; vp += 64;                             \
  }

#define QKT(B_)                                                                             \
  {                                                                                         \
    __builtin_amdgcn_s_setprio(1);                                                          \
    _Pragma("unroll") for (int st = 0; st < 4; ++st) {                                      \
      const bf16x8 kb0 = ld_bf8(rp[2 * st + 0] + (B_) * 8192);                              \
      const bf16x8 kb1 = ld_bf8(rp[2 * st + 1] + (B_) * 8192);                              \
      _Pragma("unroll") for (int qt = 0; qt < 2; ++qt) {                                    \
        f32x4 a_ = __builtin_amdgcn_mfma_f32_16x16x32_bf16(kb0, aq[qt][0], z4, 0, 0, 0);    \
        ST[qt][st] = __builtin_amdgcn_mfma_f32_16x16x32_bf16(kb1, aq[qt][1], a_, 0, 0, 0);  \
      }                                                                                     \
    }                                                                                       \
    __builtin_amdgcn_s_setprio(0);                                                          \
  }

#define SM(M0_, M1_)                                                                        \
  {                                                                                         \
    _Pragma("unroll") for (int qt = 0; qt < 2; ++qt) {                                      \
      const unsigned long long mrow = qt ? (M1_) : (M0_);                                   \
      float sv[4][4];                                                                       \
      _Pragma("unroll") for (int st = 0; st < 4; ++st) {                                    \
        const unsigned nib = (unsigned)(mrow >> (st * 16 + lg * 4)) & 0xFu;                 \
        _Pragma("unroll") for (int j = 0; j < 4; ++j) {                                     \
          float e = EXP2F(ST[qt][st][j]);                                                   \
          e = ((nib >> j) & 1u) ? 0.f : e;                                                  \
          sv[st][j] = e;                                                                    \
        }                                                                                   \
      }                                                                                     \
      rsacc[qt] += (((sv[0][0] + sv[0][1]) + (sv[0][2] + sv[0][3])) +                       \
                    ((sv[1][0] + sv[1][1]) + (sv[1][2] + sv[1][3]))) +                      \
                   (((sv[2][0] + sv[2][1]) + (sv[2][2] + sv[2][3])) +                       \
                    ((sv[3][0] + sv[3][1]) + (sv[3][2] + sv[3][3])));                       \
      uint4v pk0_, pk1_;                                                                    \
      pk0_.x = cvtpk(sv[0][0], sv[0][1]); pk0_.y = cvtpk(sv[0][2], sv[0][3]);               \
      pk0_.z = cvtpk(sv[1][0], sv[1][1]); pk0_.w = cvtpk(sv[1][2], sv[1][3]);               \
      pk1_.x = cvtpk(sv[2][0], sv[2][1]); pk1_.y = cvtpk(sv[2][2], sv[2][3]);               \
      pk1_.z = cvtpk(sv[3][0], sv[3][1]); pk1_.w = cvtpk(sv[3][2], sv[3][3]);               \
      pfrag[qt][0] = __builtin_bit_cast(bf16x8, pk0_);                                      \
      pfrag[qt][1] = __builtin_bit_cast(bf16x8, pk1_);                                      \
    }                                                                                       \
  }

#define PV(B_)                                                                              \
  {                                                                                         \
    __builtin_amdgcn_s_setprio(1);                                                          \
    _Pragma("unroll") for (int dt = 0; dt < 4; ++dt) {                                      \
      const bf16x8 v0 = ld_bf8(rp[2 * dt + 0] + (B_) * 8192 + 4096);                        \
      const bf16x8 v1 = ld_bf8(rp[2 * dt + 1] + (B_) * 8192 + 4096);                        \
      _Pragma("unroll") for (int qt = 0; qt < 2; ++qt) {                                    \
        f32x4 o_ =                                                                          \
            __builtin_amdgcn_mfma_f32_16x16x32_bf16(v0, pfrag[qt][0], OT[qt][dt], 0, 0, 0); \
        OT[qt][dt] = __builtin_amdgcn_mfma_f32_16x16x32_bf16(v1, pfrag[qt][1], o_, 0, 0, 0);\
      }                                                                                     \
    }                                                                                       \
    __builtin_amdgcn_s_setprio(0);                                                          \
  }

  // ---- prologue: tiles 0,1 staged; tile 0 computed through softmax ----
  STG(0); STG(1);
  mA0 = mpA[0]; mA1 = mpB[0];
  mB0 = mpA[1]; mB1 = mpB[1];
  const unsigned long long* mloadA = mpA + 3;
  const unsigned long long* mloadB = mpB + 3;
  __syncthreads();
  QKT(0); STG(2); SM(mA0, mA1); mA0 = mpA[2]; mA1 = mpB[2];  // pfrag(0)

#define ITER2A                                                                              \
  {                                                                                         \
    PV(0); __syncthreads();                                                                 \
    QKT(1); STG(3); SM(mB0, mB1); mB0 = mloadA[0]; mB1 = mloadB[0];                         \
    PV(1);                                                                                  \
    QKT(2); STG(0); SM(mA0, mA1); mA0 = mloadA[1]; mA1 = mloadB[1];                         \
    mloadA += 2; mloadB += 2;                                                               \
  }
#define ITER2B                                                                              \
  {                                                                                         \
    PV(2); __syncthreads();                                                                 \
    QKT(3); STG(1); SM(mB0, mB1); mB0 = mloadA[0]; mB1 = mloadB[0];                         \
    PV(3);                                                                                  \
    QKT(0); STG(2); SM(mA0, mA1); mA0 = mloadA[1]; mA1 = mloadB[1];                         \
    mloadA += 2; mloadB += 2;                                                               \
  }

  for (int i = 0; i < 7; ++i) {
    ITER2A;
    ITER2B;
  }
  // T=29 (last A): stage tile 31 only; no mp[32] read
  {
    PV(0); __syncthreads();
    QKT(1); STG(3); SM(mB0, mB1); mB0 = mloadA[0]; mB1 = mloadB[0];
    PV(1);
    QKT(2); SM(mA0, mA1);
  }
  // tail: tiles 30,31
  PV(2);
  __syncthreads();
  QKT(3); SM(mB0, mB1);
  PV(3);
#undef ITER2A
#undef ITER2B
#undef STG
#undef QKT
#undef SM
#undef PV

  // ---- epilogue: per-chain l-reduction + store x[b][q][h*64+d] = O^T[d][q]/l -
#pragma unroll
  for (int qt = 0; qt < 2; ++qt) {
    float l = rsacc[qt];
    l += __shfl_xor(l, 16);
    l += __shfl_xor(l, 32);
    const float inv = (l > 0.f) ? 1.f / l : 0.f;
    const int q = q0 + w * 32 + qt * 16 + lr;
#pragma unroll
    for (int dt = 0; dt < 4; ++dt) {
      uint2v o;
      o.x = cvtpk(OT[qt][dt][0] * inv, OT[qt][dt][1] * inv);
      o.y = cvtpk(OT[qt][dt][2] * inv, OT[qt][dt][3] * inv);
      *reinterpret_cast<uint2v*>(xg + ((size_t)(b * T_N + q)) * FDIM_N + h * 64 + dt * 16 +
                                 lg * 4) = o;
    }
  }
}

extern "C" void kernel_launch(void* const* d_in, const int* in_sizes, int n_in,
                              void* d_out, int out_size, void* d_ws, size_t ws_size,
                              hipStream_t stream) {
  const float* query = (const float*)d_in[0];
  const float* key = (const float*)d_in[1];
  const float* value = (const float*)d_in[2];
  const int* mask = (const int*)d_in[3];
  const float* Wq = (const float*)d_in[4];
  const float* bq = (const float*)d_in[5];
  const float* Wk = (const float*)d_in[6];
  const float* bk = (const float*)d_in[7];
  const float* Wv = (const float*)d_in[8];
  const float* bv = (const float*)d_in[9];
  const float* Wo = (const float*)d_in[10];
  const float* bo = (const float*)d_in[11];

  const size_t NE = (size_t)16384 * 512;
  const size_t WE = (size_t)512 * 512;
  unsigned short* qb_in = (unsigned short*)d_ws;  // bf16 inputs
  unsigned short* kb_in = qb_in + NE;
  unsigned short* vb_in = kb_in + NE;
  unsigned short* wqb = vb_in + NE;               // 4 weights bf16
  unsigned short* q_scr = wqb + 4 * WE;
  unsigned short* k_scr = q_scr + NE;
  unsigned short* vT_scr = k_scr + NE;
  unsigned long long* mbits = (unsigned long long*)(vT_scr + NE);
  unsigned short* x_scr = qb_in;  // alias: qb_in dead after gemm_q

  prep_k<<<4096, 256, 0, stream>>>(mask, Wq, Wk, Wv, Wo, query, key, value, wqb, qb_in, kb_in,
                                   vb_in, mbits);
  gemm_bt_k<0><<<512, 256, 0, stream>>>(qb_in, wqb + 0 * WE, bq, q_scr);
  gemm_bt_k<1><<<512, 256, 0, stream>>>(kb_in, wqb + 1 * WE, bk, k_scr);
  gemm_bt_k<2><<<512, 256, 0, stream>>>(vb_in, wqb + 2 * WE, bv, vT_scr);
  attn_k<<<512, 512, 0, stream>>>(q_scr, k_scr, vT_scr, mbits, x_scr);
  gemm_bt_k<3><<<512, 256, 0, stream>>>(x_scr, wqb + 3 * WE, bo, (float*)d_out);
}

// Round 15
// 213.873 us; speedup vs baseline: 1.1470x; 1.1470x over previous
//
#include <hip/hip_runtime.h>
#include <hip/hip_bf16.h>
#include <stdint.h>

#define B_N 8
#define T_N 2048
#define FDIM_N 512
#define H_N 8
#define DK_N 64

typedef float f32x4 __attribute__((ext_vector_type(4)));
typedef float float4v __attribute__((ext_vector_type(4)));
typedef __bf16 bf16x8 __attribute__((ext_vector_type(8)));
typedef unsigned short ushort8v __attribute__((ext_vector_type(8)));
typedef unsigned int uint2v __attribute__((ext_vector_type(2)));
typedef unsigned int uint4v __attribute__((ext_vector_type(4)));

#if __has_builtin(__builtin_amdgcn_exp2f)
#define EXP2F(x) __builtin_amdgcn_exp2f(x)
#else
#define EXP2F(x) exp2f(x)
#endif

static __device__ __forceinline__ unsigned short f2bf(float f) {
  unsigned int u = __builtin_bit_cast(unsigned int, f);
  u += 0x7fffu + ((u >> 16) & 1u);
  return (unsigned short)(u >> 16);
}

// v_cvt_pk_bf16_f32: lo -> bits[15:0], hi -> bits[31:16] (RNE)
static __device__ __forceinline__ unsigned cvtpk(float lo, float hi) {
  unsigned r;
  asm("v_cvt_pk_bf16_f32 %0, %1, %2" : "=v"(r) : "v"(lo), "v"(hi));
  return r;
}

static __device__ __forceinline__ void gld_lds16(const void* g, void* l) {
  __builtin_amdgcn_global_load_lds(
      (const __attribute__((address_space(1))) unsigned int*)g,
      (__attribute__((address_space(3))) unsigned int*)l, 16, 0, 0);
}

static __device__ __forceinline__ bf16x8 ld_bf8(const unsigned short* p) {
  return *reinterpret_cast<const bf16x8*>(p);
}

// elem-offset XOR swizzle for 64-elem bf16 rows (8-elem granules)
#define SWZ8(row, colE) ((colE) ^ (((row) & 7) << 3))

// combined softmax scale: 1/sqrt(64) * log2(e)  (exp2-domain softmax, no-max)
#define QSCALE 0.1803368801111244f

// ---------------- prep: mask pack + weight cvt + qkv input cvt [R12-proven] ---
__global__ __launch_bounds__(256) void prep_k(
    const int* __restrict__ m, const float* __restrict__ w0, const float* __restrict__ w1,
    const float* __restrict__ w2, const float* __restrict__ w3,
    const float* __restrict__ qin, const float* __restrict__ kin, const float* __restrict__ vin,
    unsigned short* __restrict__ wb, unsigned short* __restrict__ qb,
    unsigned short* __restrict__ kb, unsigned short* __restrict__ vb,
    unsigned long long* __restrict__ mbits) {
  const int bid = blockIdx.x;
  if (bid < 2048) {
    const size_t n = (size_t)B_N * T_N * T_N;
    const size_t stride = (size_t)2048 * 256;
    for (size_t i = (size_t)bid * 256 + threadIdx.x; i < n; i += stride) {
      unsigned long long bl = __ballot(m[i] != 0);
      if ((threadIdx.x & 63) == 0) mbits[i >> 6] = bl;
    }
  } else if (bid < 2560) {
    const int i = (bid - 2048) * 256 + threadIdx.x;  // [0, 131072)
    const int ws = i >> 15, o = i & 32767;
    const float* w = (ws == 0) ? w0 : (ws == 1) ? w1 : (ws == 2) ? w2 : w3;
    const float4v a = *reinterpret_cast<const float4v*>(w + (size_t)o * 8);
    const float4v b = *reinterpret_cast<const float4v*>(w + (size_t)o * 8 + 4);
    const ushort8v out = {f2bf(a.x), f2bf(a.y), f2bf(a.z), f2bf(a.w),
                          f2bf(b.x), f2bf(b.y), f2bf(b.z), f2bf(b.w)};
    *reinterpret_cast<ushort8v*>(wb + (size_t)i * 8) = out;
  } else {
    const unsigned total = 3u << 20;  // 3 x 2^20 ushort8-chunks
    const unsigned stride = 1536u * 256u;
    for (unsigned i = (bid - 2560) * 256 + threadIdx.x; i < total; i += stride) {
      const unsigned sel = i >> 20, off = i & 0xFFFFFu;
      const float* in = (sel == 0) ? qin : (sel == 1) ? kin : vin;
      unsigned short* out = (sel == 0) ? qb : (sel == 1) ? kb : vb;
      const float4v a = *reinterpret_cast<const float4v*>(in + (size_t)off * 8);
      const float4v b = *reinterpret_cast<const float4v*>(in + (size_t)off * 8 + 4);
      const ushort8v o = {f2bf(a.x), f2bf(a.y), f2bf(a.z), f2bf(a.w),
                          f2bf(b.x), f2bf(b.y), f2bf(b.z), f2bf(b.w)};
      *reinterpret_cast<ushort8v*>(out + (size_t)off * 8) = o;
    }
  }
}

// ---------------- single GEMM, all-bf16 m97 pattern [R12-proven] --------------
// MODE 0: q (QSCALE, layout0)  1: k (layout0)  2: vT (pi permute)  3: f32 out
template <int MODE>
__global__ __launch_bounds__(256, 3) void gemm_bt_k(const unsigned short* __restrict__ Ap,
                                                    const unsigned short* __restrict__ Wp,
                                                    const float* __restrict__ biasp,
                                                    void* __restrict__ Cp) {
  __shared__ unsigned short As[128 * 64];
  __shared__ unsigned short Bs[128 * 64];
  const int tid = threadIdx.x;
  const int lane = tid & 63, w = tid >> 6;
  const int lr = lane & 15, lg = lane >> 4;
  const int id = blockIdx.x;
  const int work = (id & 7) * 64 + (id >> 3);  // XCD swizzle over 512
  const int m0 = (work >> 2) * 128, n0 = (work & 3) * 128;
  const int wm = (w & 1) * 64, wn = (w >> 1) * 64;
  const int swz_rd = (lr & 7) << 3;

  f32x4 acc[4][4];
  const f32x4 z4 = {0.f, 0.f, 0.f, 0.f};
#pragma unroll
  for (int i = 0; i < 4; ++i)
#pragma unroll
    for (int j = 0; j < 4; ++j) acc[i][j] = z4;

  for (int k0 = 0; k0 < 512; k0 += 64) {
    __syncthreads();
#pragma unroll
    for (int i = 0; i < 4; ++i) {
      const int c = i * 256 + tid;
      const int row = c >> 3, ch = c & 7;
      const int sw = SWZ8(row, ch * 8);
      gld_lds16(Ap + (size_t)(m0 + row) * 512 + k0 + sw, &As[c * 8]);
      gld_lds16(Wp + (size_t)(n0 + row) * 512 + k0 + sw, &Bs[c * 8]);
    }
    __syncthreads();
    bf16x8 af[4][2], bw[4][2];
#pragma unroll
    for (int mt = 0; mt < 4; ++mt)
#pragma unroll
      for (int kk = 0; kk < 2; ++kk)
        af[mt][kk] = ld_bf8(&As[(wm + mt * 16 + lr) * 64 + ((kk * 32 + lg * 8) ^ swz_rd)]);
#pragma unroll
    for (int nt = 0; nt < 4; ++nt)
#pragma unroll
      for (int kk = 0; kk < 2; ++kk)
        bw[nt][kk] = ld_bf8(&Bs[(wn + nt * 16 + lr) * 64 + ((kk * 32 + lg * 8) ^ swz_rd)]);
#pragma unroll
    for (int kk = 0; kk < 2; ++kk)
#pragma unroll
      for (int mt = 0; mt < 4; ++mt)
#pragma unroll
        for (int nt = 0; nt < 4; ++nt)
          acc[mt][nt] =
              __builtin_amdgcn_mfma_f32_16x16x32_bf16(af[mt][kk], bw[nt][kk], acc[mt][nt], 0, 0, 0);
  }

#pragma unroll
  for (int nt = 0; nt < 4; ++nt) {
    const int n = n0 + wn + nt * 16 + lr;
    const float bias = biasp[n];
#pragma unroll
    for (int mt = 0; mt < 4; ++mt) {
#pragma unroll
      for (int j = 0; j < 4; ++j) {
        const int m = m0 + wm + mt * 16 + lg * 4 + j;
        float v = acc[mt][nt][j] + bias;
        const int bb = m >> 11, t = m & 2047;
        const int hh = n >> 6, d = n & 63;
        if constexpr (MODE == 0) {
          v *= QSCALE;  // fold 1/sqrt(dk)*log2e into q
          ((unsigned short*)Cp)[(((size_t)(bb * 8 + hh) * 2048 + t) << 6) + d] = f2bf(v);
        } else if constexpr (MODE == 1) {
          ((unsigned short*)Cp)[(((size_t)(bb * 8 + hh) * 2048 + t) << 6) + d] = f2bf(v);
        } else if constexpr (MODE == 2) {
          // pi: bits {0,1}->{0,1}, {2,3}->{3,4}, {4}->{2} within each 32-block
          const int tp = (t & ~31) | (((t >> 2) & 3) << 3) | (((t >> 4) & 1) << 2) | (t & 3);
          ((unsigned short*)Cp)[(((size_t)(bb * 8 + hh) * 64 + d) << 11) + tp] = f2bf(v);
        } else {
          ((float*)Cp)[(size_t)m * 512 + n] = v;
        }
      }
    }
  }
}

// ---------------- flash attention: 8 waves x 16 q-rows, cross-TILE ILP ---------
// R13 4-buffer skeleton; per barrier interval: QKT(T)->STa, QKT(T+1)->STb issued
// back-to-back (both tiles resident), then SM(a) PV(T) SM(b) PV(T+1) — QKT(T+1)
// MFMAs retire under SM(a)'s VALU, PV(T)'s under SM(b)'s. One extra ST bank
// (+16 VGPR, total ~110 < 128 at bounds(512,4)). Numerics byte-identical R12.
__global__ __launch_bounds__(512, 4) void attn_k(
    const unsigned short* __restrict__ qg, const unsigned short* __restrict__ kg,
    const unsigned short* __restrict__ vtg, const unsigned long long* __restrict__ mb,
    unsigned short* __restrict__ xg) {
  __shared__ unsigned short L[4 * 8192];  // 64 KB: 4 x {K 64x64, V^T 64x64}

  const int tid = threadIdx.x;
  const int lane = tid & 63, w = tid >> 6;  // w in [0,8)
  const int lr = lane & 15, lg = lane >> 4;
  const int swz_rd = (lr & 7) << 3;
  const int id = blockIdx.x;
  const int work = (id & 7) * 128 + (id >> 3);  // XCD swizzle: one bh per XCD chunk
  const int bh = work >> 4, qt0 = work & 15;
  const int b = bh >> 3, h = bh & 7;
  const int q0 = qt0 * 128;

  bf16x8 aq[2];
#pragma unroll
  for (int kk = 0; kk < 2; ++kk)
    aq[kk] = ld_bf8(qg + ((size_t)bh * T_N + q0 + w * 16 + lr) * DK_N + kk * 32 + lg * 8);

  // hoisted LDS read pointers (buffer/K-vs-V select folds into immediates)
  const unsigned short* rp[8];
#pragma unroll
  for (int st = 0; st < 4; ++st) {
    rp[2 * st + 0] = &L[(st * 16 + lr) * 64 + ((lg * 8) ^ swz_rd)];
    rp[2 * st + 1] = &L[(st * 16 + lr) * 64 + ((32 + lg * 8) ^ swz_rd)];
  }

  const int krow = tid >> 3, kch = tid & 7;
  const unsigned short* kp =
      kg + (size_t)bh * (T_N * DK_N) + krow * 64 + SWZ8(krow, kch * 8);
  const unsigned short* vp =
      vtg + ((size_t)bh * DK_N + krow) * T_N + SWZ8(krow, kch * 8);
  const unsigned long long* mp = mb + ((size_t)b * T_N + q0 + w * 16 + lr) * (T_N / 64);

  f32x4 OT[4];
  float rsacc = 0.f;
  const f32x4 z4 = {0.f, 0.f, 0.f, 0.f};
#pragma unroll
  for (int dt = 0; dt < 4; ++dt) OT[dt] = z4;

  f32x4 STa[4], STb[4];
  bf16x8 pfrag[2];
  unsigned long long mA, mB, mnA, mnB;

#define STG(B_)                                       \
  {                                                   \
    gld_lds16(kp, &L[(B_) * 8192 + tid * 8]);         \
    gld_lds16(vp, &L[(B_) * 8192 + 4096 + tid * 8]);  \
    kp += 4096; vp += 64;                             \
  }

#define QKT(B_, ST_)                                                                        \
  {                                                                                         \
    __builtin_amdgcn_s_setprio(1);                                                          \
    _Pragma("unroll") for (int st = 0; st < 4; ++st) {                                      \
      const bf16x8 kb0 = ld_bf8(rp[2 * st + 0] + (B_) * 8192);                              \
      const bf16x8 kb1 = ld_bf8(rp[2 * st + 1] + (B_) * 8192);                              \
      f32x4 a_ = __builtin_amdgcn_mfma_f32_16x16x32_bf16(kb0, aq[0], z4, 0, 0, 0);          \
      ST_[st] = __builtin_amdgcn_mfma_f32_16x16x32_bf16(kb1, aq[1], a_, 0, 0, 0);           \
    }                                                                                       \
    __builtin_amdgcn_s_setprio(0);                                                          \
  }

#define SM(ST_, MREG)                                                                       \
  {                                                                                         \
    float sv[4][4];                                                                         \
    _Pragma("unroll") for (int st = 0; st < 4; ++st) {                                      \
      const unsigned nib = (unsigned)((MREG) >> (st * 16 + lg * 4)) & 0xFu;                 \
      _Pragma("unroll") for (int j = 0; j < 4; ++j) {                                       \
        float e = EXP2F(ST_[st][j]);                                                        \
        e = ((nib >> j) & 1u) ? 0.f : e;                                                    \
        sv[st][j] = e;                                                                      \
      }                                                                                     \
    }                                                                                       \
    rsacc += (((sv[0][0] + sv[0][1]) + (sv[0][2] + sv[0][3])) +                             \
              ((sv[1][0] + sv[1][1]) + (sv[1][2] + sv[1][3]))) +                            \
             (((sv[2][0] + sv[2][1]) + (sv[2][2] + sv[2][3])) +                             \
              ((sv[3][0] + sv[3][1]) + (sv[3][2] + sv[3][3])));                             \
    uint4v pk0_, pk1_;                                                                      \
    pk0_.x = cvtpk(sv[0][0], sv[0][1]); pk0_.y = cvtpk(sv[0][2], sv[0][3]);                 \
    pk0_.z = cvtpk(sv[1][0], sv[1][1]); pk0_.w = cvtpk(sv[1][2], sv[1][3]);                 \
    pk1_.x = cvtpk(sv[2][0], sv[2][1]); pk1_.y = cvtpk(sv[2][2], sv[2][3]);                 \
    pk1_.z = cvtpk(sv[3][0], sv[3][1]); pk1_.w = cvtpk(sv[3][2], sv[3][3]);                 \
    pfrag[0] = __builtin_bit_cast(bf16x8, pk0_);                                            \
    pfrag[1] = __builtin_bit_cast(bf16x8, pk1_);                                            \
  }

#define PV(B_)                                                                              \
  {                                                                                         \
    __builtin_amdgcn_s_setprio(1);                                                          \
    _Pragma("unroll") for (int dt = 0; dt < 4; ++dt) {                                      \
      const bf16x8 v0 = ld_bf8(rp[2 * dt + 0] + (B_) * 8192 + 4096);                        \
      const bf16x8 v1 = ld_bf8(rp[2 * dt + 1] + (B_) * 8192 + 4096);                        \
      f32x4 o_ = __builtin_amdgcn_mfma_f32_16x16x32_bf16(v0, pfrag[0], OT[dt], 0, 0, 0);    \
      OT[dt] = __builtin_amdgcn_mfma_f32_16x16x32_bf16(v1, pfrag[1], o_, 0, 0, 0);          \
    }                                                                                       \
    __builtin_amdgcn_s_setprio(0);                                                          \
  }

  // ---- prologue: tiles 0,1 -> bufs 0,1 ----
  STG(0); STG(1);
  mA = mp[0]; mB = mp[1];
  const unsigned long long* mload = mp + 2;
  __syncthreads();

  // 7 pairs of barrier intervals cover tiles 0..27 (4 tiles per pair).
  for (int i = 0; i < 7; ++i) {
    // even interval: compute bufs 0,1; stage next pair into bufs 2,3
    QKT(0, STa); QKT(1, STb);
    STG(2); STG(3);
    mnA = mload[0]; mnB = mload[1];
    SM(STa, mA); PV(0);
    SM(STb, mB); PV(1);
    mA = mnA; mB = mnB;
    __syncthreads();
    // odd interval: compute bufs 2,3; stage next pair into bufs 0,1
    QKT(2, STa); QKT(3, STb);
    STG(0); STG(1);
    mnA = mload[2]; mnB = mload[3];
    SM(STa, mA); PV(2);
    SM(STb, mB); PV(3);
    mA = mnA; mB = mnB;
    mload += 4;
    __syncthreads();
  }
  // interval 14: tiles 28,29 (bufs 0,1); stage tiles 30,31 into bufs 2,3
  QKT(0, STa); QKT(1, STb);
  STG(2); STG(3);
  mnA = mload[0]; mnB = mload[1];
  SM(STa, mA); PV(0);
  SM(STb, mB); PV(1);
  mA = mnA; mB = mnB;
  __syncthreads();
  // interval 15: tiles 30,31 (bufs 2,3); no staging
  QKT(2, STa); QKT(3, STb);
  SM(STa, mA); PV(2);
  SM(STb, mB); PV(3);
#undef STG
#undef QKT
#undef SM
#undef PV

  // ---- epilogue: single l-reduction + store x[b][q][h*64+d] = O^T[d][q]/l ----
  {
    float l = rsacc;
    l += __shfl_xor(l, 16);
    l += __shfl_xor(l, 32);
    const float inv = (l > 0.f) ? 1.f / l : 0.f;
    const int q = q0 + w * 16 + lr;
#pragma unroll
    for (int dt = 0; dt < 4; ++dt) {
      uint2v o;
      o.x = cvtpk(OT[dt][0] * inv, OT[dt][1] * inv);
      o.y = cvtpk(OT[dt][2] * inv, OT[dt][3] * inv);
      *reinterpret_cast<uint2v*>(xg + ((size_t)(b * T_N + q)) * FDIM_N + h * 64 + dt * 16 +
                                 lg * 4) = o;
    }
  }
}

extern "C" void kernel_launch(void* const* d_in, const int* in_sizes, int n_in,
                              void* d_out, int out_size, void* d_ws, size_t ws_size,
                              hipStream_t stream) {
  const float* query = (const float*)d_in[0];
  const float* key = (const float*)d_in[1];
  const float* value = (const float*)d_in[2];
  const int* mask = (const int*)d_in[3];
  const float* Wq = (const float*)d_in[4];
  const float* bq = (const float*)d_in[5];
  const float* Wk = (const float*)d_in[6];
  const float* bk = (const float*)d_in[7];
  const float* Wv = (const float*)d_in[8];
  const float* bv = (const float*)d_in[9];
  const float* Wo = (const float*)d_in[10];
  const float* bo = (const float*)d_in[11];

  const size_t NE = (size_t)16384 * 512;
  const size_t WE = (size_t)512 * 512;
  unsigned short* qb_in = (unsigned short*)d_ws;  // bf16 inputs
  unsigned short* kb_in = qb_in + NE;
  unsigned short* vb_in = kb_in + NE;
  unsigned short* wqb = vb_in + NE;               // 4 weights bf16
  unsigned short* q_scr = wqb + 4 * WE;
  unsigned short* k_scr = q_scr + NE;
  unsigned short* vT_scr = k_scr + NE;
  unsigned long long* mbits = (unsigned long long*)(vT_scr + NE);
  unsigned short* x_scr = qb_in;  // alias: qb_in dead after gemm_q

  prep_k<<<4096, 256, 0, stream>>>(mask, Wq, Wk, Wv, Wo, query, key, value, wqb, qb_in, kb_in,
                                   vb_in, mbits);
  gemm_bt_k<0><<<512, 256, 0, stream>>>(qb_in, wqb + 0 * WE, bq, q_scr);
  gemm_bt_k<1><<<512, 256, 0, stream>>>(kb_in, wqb + 1 * WE, bk, k_scr);
  gemm_bt_k<2><<<512, 256, 0, stream>>>(vb_in, wqb + 2 * WE, bv, vT_scr);
  attn_k<<<1024, 512, 0, stream>>>(q_scr, k_scr, vT_scr, mbits, x_scr);
  gemm_bt_k<3><<<512, 256, 0, stream>>>(x_scr, wqb + 3 * WE, bo, (float*)d_out);
}

// Round 16
// 200.685 us; speedup vs baseline: 1.2223x; 1.0657x over previous
//
#include <hip/hip_runtime.h>
#include <hip/hip_bf16.h>
#include <stdint.h>

#define B_N 8
#define T_N 2048
#define FDIM_N 512
#define H_N 8
#define DK_N 64

typedef float f32x4 __attribute__((ext_vector_type(4)));
typedef float float4v __attribute__((ext_vector_type(4)));
typedef int int4v __attribute__((ext_vector_type(4)));
typedef __bf16 bf16x8 __attribute__((ext_vector_type(8)));
typedef unsigned short ushort8v __attribute__((ext_vector_type(8)));
typedef unsigned int uint2v __attribute__((ext_vector_type(2)));
typedef unsigned int uint4v __attribute__((ext_vector_type(4)));

#if __has_builtin(__builtin_amdgcn_exp2f)
#define EXP2F(x) __builtin_amdgcn_exp2f(x)
#else
#define EXP2F(x) exp2f(x)
#endif

static __device__ __forceinline__ unsigned short f2bf(float f) {
  unsigned int u = __builtin_bit_cast(unsigned int, f);
  u += 0x7fffu + ((u >> 16) & 1u);
  return (unsigned short)(u >> 16);
}

// v_cvt_pk_bf16_f32: lo -> bits[15:0], hi -> bits[31:16] (RNE)
static __device__ __forceinline__ unsigned cvtpk(float lo, float hi) {
  unsigned r;
  asm("v_cvt_pk_bf16_f32 %0, %1, %2" : "=v"(r) : "v"(lo), "v"(hi));
  return r;
}

static __device__ __forceinline__ void gld_lds16(const void* g, void* l) {
  __builtin_amdgcn_global_load_lds(
      (const __attribute__((address_space(1))) unsigned int*)g,
      (__attribute__((address_space(3))) unsigned int*)l, 16, 0, 0);
}

static __device__ __forceinline__ bf16x8 ld_bf8(const unsigned short* p) {
  return *reinterpret_cast<const bf16x8*>(p);
}

// elem-offset XOR swizzle for 64-elem bf16 rows (8-elem granules)
#define SWZ8(row, colE) ((colE) ^ (((row) & 7) << 3))

// combined softmax scale: 1/sqrt(64) * log2(e)  (exp2-domain softmax, no-max)
#define QSCALE 0.1803368801111244f

// ---------------- prep: mask pack (16B/lane) + weight cvt + qkv cvt ----------
// blocks [0,1024): mask int32 -> u64 bitmask. Each lane loads int4 (16B,
//   coalesced), nibble -> LDS (wave-sync via lgkmcnt(0), no barrier), 4 writer
//   lanes/wave assemble u64 words. Layout byte-identical to ballot version.
// blocks [1024,1536): 4 weights f32 -> bf16.
// blocks [1536,3072): q,k,v f32 -> bf16 (grid-stride).
__global__ __launch_bounds__(256) void prep_k(
    const int* __restrict__ m, const float* __restrict__ w0, const float* __restrict__ w1,
    const float* __restrict__ w2, const float* __restrict__ w3,
    const float* __restrict__ qin, const float* __restrict__ kin, const float* __restrict__ vin,
    unsigned short* __restrict__ wb, unsigned short* __restrict__ qb,
    unsigned short* __restrict__ kb, unsigned short* __restrict__ vb,
    unsigned long long* __restrict__ mbits) {
  __shared__ unsigned nibs[256];
  const int bid = blockIdx.x;
  const int tid = threadIdx.x;
  if (bid < 1024) {
    const size_t nchunks = (size_t)B_N * T_N * T_N / 4;  // 8.4M int4-chunks
    const size_t stride = (size_t)1024 * 256;
    const int l = tid & 63;
    for (size_t c = (size_t)bid * 256 + tid; c < nchunks; c += stride) {
      const int4v v = *reinterpret_cast<const int4v*>(m + c * 4);
      const unsigned nib = (v.x != 0 ? 1u : 0u) | (v.y != 0 ? 2u : 0u) |
                           (v.z != 0 ? 4u : 0u) | (v.w != 0 ? 8u : 0u);
      nibs[tid] = nib;
      asm volatile("s_waitcnt lgkmcnt(0)" ::: "memory");
      if (l < 4) {
        const int base = (tid & ~63) + l * 16;
        unsigned long long wbits = 0;
#pragma unroll
        for (int i = 0; i < 16; ++i)
          wbits |= (unsigned long long)(nibs[base + i] & 0xFu) << (4 * i);
        mbits[(c - l) / 16 + l] = wbits;
      }
      asm volatile("s_waitcnt lgkmcnt(0)" ::: "memory");  // reads done before next overwrite
    }
  } else if (bid < 1536) {
    const int i = (bid - 1024) * 256 + tid;  // [0, 131072)
    const int ws = i >> 15, o = i & 32767;
    const float* w = (ws == 0) ? w0 : (ws == 1) ? w1 : (ws == 2) ? w2 : w3;
    const float4v a = *reinterpret_cast<const float4v*>(w + (size_t)o * 8);
    const float4v b = *reinterpret_cast<const float4v*>(w + (size_t)o * 8 + 4);
    const ushort8v out = {f2bf(a.x), f2bf(a.y), f2bf(a.z), f2bf(a.w),
                          f2bf(b.x), f2bf(b.y), f2bf(b.z), f2bf(b.w)};
    *reinterpret_cast<ushort8v*>(wb + (size_t)i * 8) = out;
  } else {
    const unsigned total = 3u << 20;  // 3 x 2^20 ushort8-chunks
    const unsigned stride = 1536u * 256u;
    for (unsigned i = (bid - 1536) * 256 + tid; i < total; i += stride) {
      const unsigned sel = i >> 20, off = i & 0xFFFFFu;
      const float* in = (sel == 0) ? qin : (sel == 1) ? kin : vin;
      unsigned short* out = (sel == 0) ? qb : (sel == 1) ? kb : vb;
      const float4v a = *reinterpret_cast<const float4v*>(in + (size_t)off * 8);
      const float4v b = *reinterpret_cast<const float4v*>(in + (size_t)off * 8 + 4);
      const ushort8v o = {f2bf(a.x), f2bf(a.y), f2bf(a.z), f2bf(a.w),
                          f2bf(b.x), f2bf(b.y), f2bf(b.z), f2bf(b.w)};
      *reinterpret_cast<ushort8v*>(out + (size_t)off * 8) = o;
    }
  }
}

// ---------------- single GEMM, all-bf16 m97 pattern [R12-proven] --------------
// MODE 0: q (QSCALE, layout0)  1: k (layout0)  2: vT (pi permute)  3: f32 out
template <int MODE>
__global__ __launch_bounds__(256, 3) void gemm_bt_k(const unsigned short* __restrict__ Ap,
                                                    const unsigned short* __restrict__ Wp,
                                                    const float* __restrict__ biasp,
                                                    void* __restrict__ Cp) {
  __shared__ unsigned short As[128 * 64];
  __shared__ unsigned short Bs[128 * 64];
  const int tid = threadIdx.x;
  const int lane = tid & 63, w = tid >> 6;
  const int lr = lane & 15, lg = lane >> 4;
  const int id = blockIdx.x;
  const int work = (id & 7) * 64 + (id >> 3);  // XCD swizzle over 512
  const int m0 = (work >> 2) * 128, n0 = (work & 3) * 128;
  const int wm = (w & 1) * 64, wn = (w >> 1) * 64;
  const int swz_rd = (lr & 7) << 3;

  f32x4 acc[4][4];
  const f32x4 z4 = {0.f, 0.f, 0.f, 0.f};
#pragma unroll
  for (int i = 0; i < 4; ++i)
#pragma unroll
    for (int j = 0; j < 4; ++j) acc[i][j] = z4;

  for (int k0 = 0; k0 < 512; k0 += 64) {
    __syncthreads();
#pragma unroll
    for (int i = 0; i < 4; ++i) {
      const int c = i * 256 + tid;
      const int row = c >> 3, ch = c & 7;
      const int sw = SWZ8(row, ch * 8);
      gld_lds16(Ap + (size_t)(m0 + row) * 512 + k0 + sw, &As[c * 8]);
      gld_lds16(Wp + (size_t)(n0 + row) * 512 + k0 + sw, &Bs[c * 8]);
    }
    __syncthreads();
    bf16x8 af[4][2], bw[4][2];
#pragma unroll
    for (int mt = 0; mt < 4; ++mt)
#pragma unroll
      for (int kk = 0; kk < 2; ++kk)
        af[mt][kk] = ld_bf8(&As[(wm + mt * 16 + lr) * 64 + ((kk * 32 + lg * 8) ^ swz_rd)]);
#pragma unroll
    for (int nt = 0; nt < 4; ++nt)
#pragma unroll
      for (int kk = 0; kk < 2; ++kk)
        bw[nt][kk] = ld_bf8(&Bs[(wn + nt * 16 + lr) * 64 + ((kk * 32 + lg * 8) ^ swz_rd)]);
#pragma unroll
    for (int kk = 0; kk < 2; ++kk)
#pragma unroll
      for (int mt = 0; mt < 4; ++mt)
#pragma unroll
        for (int nt = 0; nt < 4; ++nt)
          acc[mt][nt] =
              __builtin_amdgcn_mfma_f32_16x16x32_bf16(af[mt][kk], bw[nt][kk], acc[mt][nt], 0, 0, 0);
  }

#pragma unroll
  for (int nt = 0; nt < 4; ++nt) {
    const int n = n0 + wn + nt * 16 + lr;
    const float bias = biasp[n];
#pragma unroll
    for (int mt = 0; mt < 4; ++mt) {
#pragma unroll
      for (int j = 0; j < 4; ++j) {
        const int m = m0 + wm + mt * 16 + lg * 4 + j;
        float v = acc[mt][nt][j] + bias;
        const int bb = m >> 11, t = m & 2047;
        const int hh = n >> 6, d = n & 63;
        if constexpr (MODE == 0) {
          v *= QSCALE;  // fold 1/sqrt(dk)*log2e into q
          ((unsigned short*)Cp)[(((size_t)(bb * 8 + hh) * 2048 + t) << 6) + d] = f2bf(v);
        } else if constexpr (MODE == 1) {
          ((unsigned short*)Cp)[(((size_t)(bb * 8 + hh) * 2048 + t) << 6) + d] = f2bf(v);
        } else if constexpr (MODE == 2) {
          // pi: bits {0,1}->{0,1}, {2,3}->{3,4}, {4}->{2} within each 32-block
          const int tp = (t & ~31) | (((t >> 2) & 3) << 3) | (((t >> 4) & 1) << 2) | (t & 3);
          ((unsigned short*)Cp)[(((size_t)(bb * 8 + hh) * 64 + d) << 11) + tp] = f2bf(v);
        } else {
          ((float*)Cp)[(size_t)m * 512 + n] = v;
        }
      }
    }
  }
}

// ---------------- flash attention: 8 waves x 16 q-rows, cross-TILE ILP [R15] ---
__global__ __launch_bounds__(512, 4) void attn_k(
    const unsigned short* __restrict__ qg, const unsigned short* __restrict__ kg,
    const unsigned short* __restrict__ vtg, const unsigned long long* __restrict__ mb,
    unsigned short* __restrict__ xg) {
  __shared__ unsigned short L[4 * 8192];  // 64 KB: 4 x {K 64x64, V^T 64x64}

  const int tid = threadIdx.x;
  const int lane = tid & 63, w = tid >> 6;  // w in [0,8)
  const int lr = lane & 15, lg = lane >> 4;
  const int swz_rd = (lr & 7) << 3;
  const int id = blockIdx.x;
  const int work = (id & 7) * 128 + (id >> 3);  // XCD swizzle: one bh per XCD chunk
  const int bh = work >> 4, qt0 = work & 15;
  const int b = bh >> 3, h = bh & 7;
  const int q0 = qt0 * 128;

  bf16x8 aq[2];
#pragma unroll
  for (int kk = 0; kk < 2; ++kk)
    aq[kk] = ld_bf8(qg + ((size_t)bh * T_N + q0 + w * 16 + lr) * DK_N + kk * 32 + lg * 8);

  // hoisted LDS read pointers (buffer/K-vs-V select folds into immediates)
  const unsigned short* rp[8];
#pragma unroll
  for (int st = 0; st < 4; ++st) {
    rp[2 * st + 0] = &L[(st * 16 + lr) * 64 + ((lg * 8) ^ swz_rd)];
    rp[2 * st + 1] = &L[(st * 16 + lr) * 64 + ((32 + lg * 8) ^ swz_rd)];
  }

  const int krow = tid >> 3, kch = tid & 7;
  const unsigned short* kp =
      kg + (size_t)bh * (T_N * DK_N) + krow * 64 + SWZ8(krow, kch * 8);
  const unsigned short* vp =
      vtg + ((size_t)bh * DK_N + krow) * T_N + SWZ8(krow, kch * 8);
  const unsigned long long* mp = mb + ((size_t)b * T_N + q0 + w * 16 + lr) * (T_N / 64);

  f32x4 OT[4];
  float rsacc = 0.f;
  const f32x4 z4 = {0.f, 0.f, 0.f, 0.f};
#pragma unroll
  for (int dt = 0; dt < 4; ++dt) OT[dt] = z4;

  f32x4 STa[4], STb[4];
  bf16x8 pfrag[2];
  unsigned long long mA, mB, mnA, mnB;

#define STG(B_)                                       \
  {                                                   \
    gld_lds16(kp, &L[(B_) * 8192 + tid * 8]);         \
    gld_lds16(vp, &L[(B_) * 8192 + 4096 + tid * 8]);  \
    kp += 4096; vp += 64;                             \
  }

#define QKT(B_, ST_)                                                                        \
  {                                                                                         \
    __builtin_amdgcn_s_setprio(1);                                                          \
    _Pragma("unroll") for (int st = 0; st < 4; ++st) {                                      \
      const bf16x8 kb0 = ld_bf8(rp[2 * st + 0] + (B_) * 8192);                              \
      const bf16x8 kb1 = ld_bf8(rp[2 * st + 1] + (B_) * 8192);                              \
      f32x4 a_ = __builtin_amdgcn_mfma_f32_16x16x32_bf16(kb0, aq[0], z4, 0, 0, 0);          \
      ST_[st] = __builtin_amdgcn_mfma_f32_16x16x32_bf16(kb1, aq[1], a_, 0, 0, 0);           \
    }                                                                                       \
    __builtin_amdgcn_s_setprio(0);                                                          \
  }

#define SM(ST_, MREG)                                                                       \
  {                                                                                         \
    float sv[4][4];                                                                         \
    _Pragma("unroll") for (int st = 0; st < 4; ++st) {                                      \
      const unsigned nib = (unsigned)((MREG) >> (st * 16 + lg * 4)) & 0xFu;                 \
      _Pragma("unroll") for (int j = 0; j < 4; ++j) {                                       \
        float e = EXP2F(ST_[st][j]);                                                        \
        e = ((nib >> j) & 1u) ? 0.f : e;                                                    \
        sv[st][j] = e;                                                                      \
      }                                                                                     \
    }                                                                                       \
    rsacc += (((sv[0][0] + sv[0][1]) + (sv[0][2] + sv[0][3])) +                             \
              ((sv[1][0] + sv[1][1]) + (sv[1][2] + sv[1][3]))) +                            \
             (((sv[2][0] + sv[2][1]) + (sv[2][2] + sv[2][3])) +                             \
              ((sv[3][0] + sv[3][1]) + (sv[3][2] + sv[3][3])));                             \
    uint4v pk0_, pk1_;                                                                      \
    pk0_.x = cvtpk(sv[0][0], sv[0][1]); pk0_.y = cvtpk(sv[0][2], sv[0][3]);                 \
    pk0_.z = cvtpk(sv[1][0], sv[1][1]); pk0_.w = cvtpk(sv[1][2], sv[1][3]);                 \
    pk1_.x = cvtpk(sv[2][0], sv[2][1]); pk1_.y = cvtpk(sv[2][2], sv[2][3]);                 \
    pk1_.z = cvtpk(sv[3][0], sv[3][1]); pk1_.w = cvtpk(sv[3][2], sv[3][3]);                 \
    pfrag[0] = __builtin_bit_cast(bf16x8, pk0_);                                            \
    pfrag[1] = __builtin_bit_cast(bf16x8, pk1_);                                            \
  }

#define PV(B_)                                                                              \
  {                                                                                         \
    __builtin_amdgcn_s_setprio(1);                                                          \
    _Pragma("unroll") for (int dt = 0; dt < 4; ++dt) {                                      \
      const bf16x8 v0 = ld_bf8(rp[2 * dt + 0] + (B_) * 8192 + 4096);                        \
      const bf16x8 v1 = ld_bf8(rp[2 * dt + 1] + (B_) * 8192 + 4096);                        \
      f32x4 o_ = __builtin_amdgcn_mfma_f32_16x16x32_bf16(v0, pfrag[0], OT[dt], 0, 0, 0);    \
      OT[dt] = __builtin_amdgcn_mfma_f32_16x16x32_bf16(v1, pfrag[1], o_, 0, 0, 0);          \
    }                                                                                       \
    __builtin_amdgcn_s_setprio(0);                                                          \
  }

  // ---- prologue: tiles 0,1 -> bufs 0,1 ----
  STG(0); STG(1);
  mA = mp[0]; mB = mp[1];
  const unsigned long long* mload = mp + 2;
  __syncthreads();

  // 7 pairs of barrier intervals cover tiles 0..27 (4 tiles per pair).
  for (int i = 0; i < 7; ++i) {
    QKT(0, STa); QKT(1, STb);
    STG(2); STG(3);
    mnA = mload[0]; mnB = mload[1];
    SM(STa, mA); PV(0);
    SM(STb, mB); PV(1);
    mA = mnA; mB = mnB;
    __syncthreads();
    QKT(2, STa); QKT(3, STb);
    STG(0); STG(1);
    mnA = mload[2]; mnB = mload[3];
    SM(STa, mA); PV(2);
    SM(STb, mB); PV(3);
    mA = mnA; mB = mnB;
    mload += 4;
    __syncthreads();
  }
  // interval 14: tiles 28,29 (bufs 0,1); stage tiles 30,31 into bufs 2,3
  QKT(0, STa); QKT(1, STb);
  STG(2); STG(3);
  mnA = mload[0]; mnB = mload[1];
  SM(STa, mA); PV(0);
  SM(STb, mB); PV(1);
  mA = mnA; mB = mnB;
  __syncthreads();
  // interval 15: tiles 30,31 (bufs 2,3); no staging
  QKT(2, STa); QKT(3, STb);
  SM(STa, mA); PV(2);
  SM(STb, mB); PV(3);
#undef STG
#undef QKT
#undef SM
#undef PV

  // ---- epilogue: single l-reduction + store x[b][q][h*64+d] = O^T[d][q]/l ----
  {
    float l = rsacc;
    l += __shfl_xor(l, 16);
    l += __shfl_xor(l, 32);
    const float inv = (l > 0.f) ? 1.f / l : 0.f;
    const int q = q0 + w * 16 + lr;
#pragma unroll
    for (int dt = 0; dt < 4; ++dt) {
      uint2v o;
      o.x = cvtpk(OT[dt][0] * inv, OT[dt][1] * inv);
      o.y = cvtpk(OT[dt][2] * inv, OT[dt][3] * inv);
      *reinterpret_cast<uint2v*>(xg + ((size_t)(b * T_N + q)) * FDIM_N + h * 64 + dt * 16 +
                                 lg * 4) = o;
    }
  }
}

extern "C" void kernel_launch(void* const* d_in, const int* in_sizes, int n_in,
                              void* d_out, int out_size, void* d_ws, size_t ws_size,
                              hipStream_t stream) {
  const float* query = (const float*)d_in[0];
  const float* key = (const float*)d_in[1];
  const float* value = (const float*)d_in[2];
  const int* mask = (const int*)d_in[3];
  const float* Wq = (const float*)d_in[4];
  const float* bq = (const float*)d_in[5];
  const float* Wk = (const float*)d_in[6];
  const float* bk = (const float*)d_in[7];
  const float* Wv = (const float*)d_in[8];
  const float* bv = (const float*)d_in[9];
  const float* Wo = (const float*)d_in[10];
  const float* bo = (const float*)d_in[11];

  const size_t NE = (size_t)16384 * 512;
  const size_t WE = (size_t)512 * 512;
  unsigned short* qb_in = (unsigned short*)d_ws;  // bf16 inputs
  unsigned short* kb_in = qb_in + NE;
  unsigned short* vb_in = kb_in + NE;
  unsigned short* wqb = vb_in + NE;               // 4 weights bf16
  unsigned short* q_scr = wqb + 4 * WE;
  unsigned short* k_scr = q_scr + NE;
  unsigned short* vT_scr = k_scr + NE;
  unsigned long long* mbits = (unsigned long long*)(vT_scr + NE);
  unsigned short* x_scr = qb_in;  // alias: qb_in dead after gemm_q

  prep_k<<<3072, 256, 0, stream>>>(mask, Wq, Wk, Wv, Wo, query, key, value, wqb, qb_in, kb_in,
                                   vb_in, mbits);
  gemm_bt_k<0><<<512, 256, 0, stream>>>(qb_in, wqb + 0 * WE, bq, q_scr);
  gemm_bt_k<1><<<512, 256, 0, stream>>>(kb_in, wqb + 1 * WE, bk, k_scr);
  gemm_bt_k<2><<<512, 256, 0, stream>>>(vb_in, wqb + 2 * WE, bv, vT_scr);
  attn_k<<<1024, 512, 0, stream>>>(q_scr, k_scr, vT_scr, mbits, x_scr);
  gemm_bt_k<3><<<512, 256, 0, stream>>>(x_scr, wqb + 3 * WE, bo, (float*)d_out);
}

// Round 17
// 199.040 us; speedup vs baseline: 1.2325x; 1.0083x over previous
//
#include <hip/hip_runtime.h>
#include <hip/hip_bf16.h>
#include <stdint.h>

#define B_N 8
#define T_N 2048
#define FDIM_N 512
#define H_N 8
#define DK_N 64

typedef float f32x4 __attribute__((ext_vector_type(4)));
typedef float f32x2 __attribute__((ext_vector_type(2)));
typedef float float4v __attribute__((ext_vector_type(4)));
typedef int int4v __attribute__((ext_vector_type(4)));
typedef __bf16 bf16x8 __attribute__((ext_vector_type(8)));
typedef unsigned short ushort8v __attribute__((ext_vector_type(8)));
typedef unsigned int uint2v __attribute__((ext_vector_type(2)));
typedef unsigned int uint4v __attribute__((ext_vector_type(4)));

#if __has_builtin(__builtin_amdgcn_exp2f)
#define EXP2F(x) __builtin_amdgcn_exp2f(x)
#else
#define EXP2F(x) exp2f(x)
#endif

static __device__ __forceinline__ unsigned short f2bf(float f) {
  unsigned int u = __builtin_bit_cast(unsigned int, f);
  u += 0x7fffu + ((u >> 16) & 1u);
  return (unsigned short)(u >> 16);
}

// v_cvt_pk_bf16_f32: lo -> bits[15:0], hi -> bits[31:16] (RNE)
static __device__ __forceinline__ unsigned cvtpk(float lo, float hi) {
  unsigned r;
  asm("v_cvt_pk_bf16_f32 %0, %1, %2" : "=v"(r) : "v"(lo), "v"(hi));
  return r;
}

static __device__ __forceinline__ void gld_lds16(const void* g, void* l) {
  __builtin_amdgcn_global_load_lds(
      (const __attribute__((address_space(1))) unsigned int*)g,
      (__attribute__((address_space(3))) unsigned int*)l, 16, 0, 0);
}

static __device__ __forceinline__ bf16x8 ld_bf8(const unsigned short* p) {
  return *reinterpret_cast<const bf16x8*>(p);
}

// elem-offset XOR swizzle for 64-elem bf16 rows (8-elem granules)
#define SWZ8(row, colE) ((colE) ^ (((row) & 7) << 3))

// combined softmax scale: 1/sqrt(64) * log2(e)  (exp2-domain softmax, no-max)
#define QSCALE 0.1803368801111244f

// ---------------- prep: mask pack (16B/lane) + weight cvt + qkv cvt [R16] -----
__global__ __launch_bounds__(256) void prep_k(
    const int* __restrict__ m, const float* __restrict__ w0, const float* __restrict__ w1,
    const float* __restrict__ w2, const float* __restrict__ w3,
    const float* __restrict__ qin, const float* __restrict__ kin, const float* __restrict__ vin,
    unsigned short* __restrict__ wb, unsigned short* __restrict__ qb,
    unsigned short* __restrict__ kb, unsigned short* __restrict__ vb,
    unsigned long long* __restrict__ mbits) {
  __shared__ unsigned nibs[256];
  const int bid = blockIdx.x;
  const int tid = threadIdx.x;
  if (bid < 1024) {
    const size_t nchunks = (size_t)B_N * T_N * T_N / 4;  // 8.4M int4-chunks
    const size_t stride = (size_t)1024 * 256;
    const int l = tid & 63;
    for (size_t c = (size_t)bid * 256 + tid; c < nchunks; c += stride) {
      const int4v v = *reinterpret_cast<const int4v*>(m + c * 4);
      const unsigned nib = (v.x != 0 ? 1u : 0u) | (v.y != 0 ? 2u : 0u) |
                           (v.z != 0 ? 4u : 0u) | (v.w != 0 ? 8u : 0u);
      nibs[tid] = nib;
      asm volatile("s_waitcnt lgkmcnt(0)" ::: "memory");
      if (l < 4) {
        const int base = (tid & ~63) + l * 16;
        unsigned long long wbits = 0;
#pragma unroll
        for (int i = 0; i < 16; ++i)
          wbits |= (unsigned long long)(nibs[base + i] & 0xFu) << (4 * i);
        mbits[(c - l) / 16 + l] = wbits;
      }
      asm volatile("s_waitcnt lgkmcnt(0)" ::: "memory");  // reads done before next overwrite
    }
  } else if (bid < 1536) {
    const int i = (bid - 1024) * 256 + tid;  // [0, 131072)
    const int ws = i >> 15, o = i & 32767;
    const float* w = (ws == 0) ? w0 : (ws == 1) ? w1 : (ws == 2) ? w2 : w3;
    const float4v a = *reinterpret_cast<const float4v*>(w + (size_t)o * 8);
    const float4v b = *reinterpret_cast<const float4v*>(w + (size_t)o * 8 + 4);
    const ushort8v out = {f2bf(a.x), f2bf(a.y), f2bf(a.z), f2bf(a.w),
                          f2bf(b.x), f2bf(b.y), f2bf(b.z), f2bf(b.w)};
    *reinterpret_cast<ushort8v*>(wb + (size_t)i * 8) = out;
  } else {
    const unsigned total = 3u << 20;  // 3 x 2^20 ushort8-chunks
    const unsigned stride = 1536u * 256u;
    for (unsigned i = (bid - 1536) * 256 + tid; i < total; i += stride) {
      const unsigned sel = i >> 20, off = i & 0xFFFFFu;
      const float* in = (sel == 0) ? qin : (sel == 1) ? kin : vin;
      unsigned short* out = (sel == 0) ? qb : (sel == 1) ? kb : vb;
      const float4v a = *reinterpret_cast<const float4v*>(in + (size_t)off * 8);
      const float4v b = *reinterpret_cast<const float4v*>(in + (size_t)off * 8 + 4);
      const ushort8v o = {f2bf(a.x), f2bf(a.y), f2bf(a.z), f2bf(a.w),
                          f2bf(b.x), f2bf(b.y), f2bf(b.z), f2bf(b.w)};
      *reinterpret_cast<ushort8v*>(out + (size_t)off * 8) = o;
    }
  }
}

// ---------------- single GEMM, all-bf16 m97 pattern [R12-proven] --------------
// MODE 0: q (QSCALE, layout0)  1: k (layout0)  2: vT (pi permute)  3: f32 out
template <int MODE>
__global__ __launch_bounds__(256, 3) void gemm_bt_k(const unsigned short* __restrict__ Ap,
                                                    const unsigned short* __restrict__ Wp,
                                                    const float* __restrict__ biasp,
                                                    void* __restrict__ Cp) {
  __shared__ unsigned short As[128 * 64];
  __shared__ unsigned short Bs[128 * 64];
  const int tid = threadIdx.x;
  const int lane = tid & 63, w = tid >> 6;
  const int lr = lane & 15, lg = lane >> 4;
  const int id = blockIdx.x;
  const int work = (id & 7) * 64 + (id >> 3);  // XCD swizzle over 512
  const int m0 = (work >> 2) * 128, n0 = (work & 3) * 128;
  const int wm = (w & 1) * 64, wn = (w >> 1) * 64;
  const int swz_rd = (lr & 7) << 3;

  f32x4 acc[4][4];
  const f32x4 z4 = {0.f, 0.f, 0.f, 0.f};
#pragma unroll
  for (int i = 0; i < 4; ++i)
#pragma unroll
    for (int j = 0; j < 4; ++j) acc[i][j] = z4;

  for (int k0 = 0; k0 < 512; k0 += 64) {
    __syncthreads();
#pragma unroll
    for (int i = 0; i < 4; ++i) {
      const int c = i * 256 + tid;
      const int row = c >> 3, ch = c & 7;
      const int sw = SWZ8(row, ch * 8);
      gld_lds16(Ap + (size_t)(m0 + row) * 512 + k0 + sw, &As[c * 8]);
      gld_lds16(Wp + (size_t)(n0 + row) * 512 + k0 + sw, &Bs[c * 8]);
    }
    __syncthreads();
    bf16x8 af[4][2], bw[4][2];
#pragma unroll
    for (int mt = 0; mt < 4; ++mt)
#pragma unroll
      for (int kk = 0; kk < 2; ++kk)
        af[mt][kk] = ld_bf8(&As[(wm + mt * 16 + lr) * 64 + ((kk * 32 + lg * 8) ^ swz_rd)]);
#pragma unroll
    for (int nt = 0; nt < 4; ++nt)
#pragma unroll
      for (int kk = 0; kk < 2; ++kk)
        bw[nt][kk] = ld_bf8(&Bs[(wn + nt * 16 + lr) * 64 + ((kk * 32 + lg * 8) ^ swz_rd)]);
#pragma unroll
    for (int kk = 0; kk < 2; ++kk)
#pragma unroll
      for (int mt = 0; mt < 4; ++mt)
#pragma unroll
        for (int nt = 0; nt < 4; ++nt)
          acc[mt][nt] =
              __builtin_amdgcn_mfma_f32_16x16x32_bf16(af[mt][kk], bw[nt][kk], acc[mt][nt], 0, 0, 0);
  }

#pragma unroll
  for (int nt = 0; nt < 4; ++nt) {
    const int n = n0 + wn + nt * 16 + lr;
    const float bias = biasp[n];
#pragma unroll
    for (int mt = 0; mt < 4; ++mt) {
#pragma unroll
      for (int j = 0; j < 4; ++j) {
        const int m = m0 + wm + mt * 16 + lg * 4 + j;
        float v = acc[mt][nt][j] + bias;
        const int bb = m >> 11, t = m & 2047;
        const int hh = n >> 6, d = n & 63;
        if constexpr (MODE == 0) {
          v *= QSCALE;  // fold 1/sqrt(dk)*log2e into q
          ((unsigned short*)Cp)[(((size_t)(bb * 8 + hh) * 2048 + t) << 6) + d] = f2bf(v);
        } else if constexpr (MODE == 1) {
          ((unsigned short*)Cp)[(((size_t)(bb * 8 + hh) * 2048 + t) << 6) + d] = f2bf(v);
        } else if constexpr (MODE == 2) {
          // pi: bits {0,1}->{0,1}, {2,3}->{3,4}, {4}->{2} within each 32-block
          const int tp = (t & ~31) | (((t >> 2) & 3) << 3) | (((t >> 4) & 1) << 2) | (t & 3);
          ((unsigned short*)Cp)[(((size_t)(bb * 8 + hh) * 64 + d) << 11) + tp] = f2bf(v);
        } else {
          ((float*)Cp)[(size_t)m * 512 + n] = v;
        }
      }
    }
  }
}

// ---------------- flash attention: 8 waves x 16 q-rows, cross-TILE ILP ---------
// R16 structure; SM block VALU diet: mask handled as 2x u32 with a single
// variable pre-shift (all nibbles via fixed-immediate shifts), l-sum via
// pairwise float2 adds (v_pk_add_f32). Numerics byte-identical.
__global__ __launch_bounds__(512, 4) void attn_k(
    const unsigned short* __restrict__ qg, const unsigned short* __restrict__ kg,
    const unsigned short* __restrict__ vtg, const unsigned long long* __restrict__ mb,
    unsigned short* __restrict__ xg) {
  __shared__ unsigned short L[4 * 8192];  // 64 KB: 4 x {K 64x64, V^T 64x64}

  const int tid = threadIdx.x;
  const int lane = tid & 63, w = tid >> 6;  // w in [0,8)
  const int lr = lane & 15, lg = lane >> 4;
  const int swz_rd = (lr & 7) << 3;
  const int id = blockIdx.x;
  const int work = (id & 7) * 128 + (id >> 3);  // XCD swizzle: one bh per XCD chunk
  const int bh = work >> 4, qt0 = work & 15;
  const int b = bh >> 3, h = bh & 7;
  const int q0 = qt0 * 128;

  bf16x8 aq[2];
#pragma unroll
  for (int kk = 0; kk < 2; ++kk)
    aq[kk] = ld_bf8(qg + ((size_t)bh * T_N + q0 + w * 16 + lr) * DK_N + kk * 32 + lg * 8);

  // hoisted LDS read pointers (buffer/K-vs-V select folds into immediates)
  const unsigned short* rp[8];
#pragma unroll
  for (int st = 0; st < 4; ++st) {
    rp[2 * st + 0] = &L[(st * 16 + lr) * 64 + ((lg * 8) ^ swz_rd)];
    rp[2 * st + 1] = &L[(st * 16 + lr) * 64 + ((32 + lg * 8) ^ swz_rd)];
  }

  const int krow = tid >> 3, kch = tid & 7;
  const unsigned short* kp =
      kg + (size_t)bh * (T_N * DK_N) + krow * 64 + SWZ8(krow, kch * 8);
  const unsigned short* vp =
      vtg + ((size_t)bh * DK_N + krow) * T_N + SWZ8(krow, kch * 8);
  const unsigned long long* mp = mb + ((size_t)b * T_N + q0 + w * 16 + lr) * (T_N / 64);
  const int lsh = lg * 4;

  f32x4 OT[4];
  float rsacc = 0.f;
  const f32x4 z4 = {0.f, 0.f, 0.f, 0.f};
#pragma unroll
  for (int dt = 0; dt < 4; ++dt) OT[dt] = z4;

  f32x4 STa[4], STb[4];
  bf16x8 pfrag[2];
  uint2v mA, mB, mnA, mnB;

#define MRD(i) (*reinterpret_cast<const uint2v*>(&mload[i]))

#define STG(B_)                                       \
  {                                                   \
    gld_lds16(kp, &L[(B_) * 8192 + tid * 8]);         \
    gld_lds16(vp, &L[(B_) * 8192 + 4096 + tid * 8]);  \
    kp += 4096; vp += 64;                             \
  }

#define QKT(B_, ST_)                                                                        \
  {                                                                                         \
    __builtin_amdgcn_s_setprio(1);                                                          \
    _Pragma("unroll") for (int st = 0; st < 4; ++st) {                                      \
      const bf16x8 kb0 = ld_bf8(rp[2 * st + 0] + (B_) * 8192);                              \
      const bf16x8 kb1 = ld_bf8(rp[2 * st + 1] + (B_) * 8192);                              \
      f32x4 a_ = __builtin_amdgcn_mfma_f32_16x16x32_bf16(kb0, aq[0], z4, 0, 0, 0);          \
      ST_[st] = __builtin_amdgcn_mfma_f32_16x16x32_bf16(kb1, aq[1], a_, 0, 0, 0);           \
    }                                                                                       \
    __builtin_amdgcn_s_setprio(0);                                                          \
  }

#define SM(ST_, MW)                                                                         \
  {                                                                                         \
    const unsigned mlo_ = (MW).x >> lsh;                                                    \
    const unsigned mhi_ = (MW).y >> lsh;                                                    \
    const unsigned nb_[4] = {mlo_ & 0xFu, (mlo_ >> 16) & 0xFu,                              \
                             mhi_ & 0xFu, (mhi_ >> 16) & 0xFu};                             \
    float sv[4][4];                                                                         \
    _Pragma("unroll") for (int st = 0; st < 4; ++st) {                                      \
      _Pragma("unroll") for (int j = 0; j < 4; ++j) {                                       \
        float e = EXP2F(ST_[st][j]);                                                        \
        e = ((nb_[st] >> j) & 1u) ? 0.f : e;                                                \
        sv[st][j] = e;                                                                      \
      }                                                                                     \
    }                                                                                       \
    {                                                                                       \
      f32x2 t0 = (f32x2){sv[0][0], sv[0][1]} + (f32x2){sv[1][0], sv[1][1]};                 \
      f32x2 t1 = (f32x2){sv[0][2], sv[0][3]} + (f32x2){sv[1][2], sv[1][3]};                 \
      f32x2 t2 = (f32x2){sv[2][0], sv[2][1]} + (f32x2){sv[3][0], sv[3][1]};                 \
      f32x2 t3 = (f32x2){sv[2][2], sv[2][3]} + (f32x2){sv[3][2], sv[3][3]};                 \
      const f32x2 u_ = (t0 + t1) + (t2 + t3);                                               \
      rsacc += u_.x + u_.y;                                                                 \
    }                                                                                       \
    uint4v pk0_, pk1_;                                                                      \
    pk0_.x = cvtpk(sv[0][0], sv[0][1]); pk0_.y = cvtpk(sv[0][2], sv[0][3]);                 \
    pk0_.z = cvtpk(sv[1][0], sv[1][1]); pk0_.w = cvtpk(sv[1][2], sv[1][3]);                 \
    pk1_.x = cvtpk(sv[2][0], sv[2][1]); pk1_.y = cvtpk(sv[2][2], sv[2][3]);                 \
    pk1_.z = cvtpk(sv[3][0], sv[3][1]); pk1_.w = cvtpk(sv[3][2], sv[3][3]);                 \
    pfrag[0] = __builtin_bit_cast(bf16x8, pk0_);                                            \
    pfrag[1] = __builtin_bit_cast(bf16x8, pk1_);                                            \
  }

#define PV(B_)                                                                              \
  {                                                                                         \
    __builtin_amdgcn_s_setprio(1);                                                          \
    _Pragma("unroll") for (int dt = 0; dt < 4; ++dt) {                                      \
      const bf16x8 v0 = ld_bf8(rp[2 * dt + 0] + (B_) * 8192 + 4096);                        \
      const bf16x8 v1 = ld_bf8(rp[2 * dt + 1] + (B_) * 8192 + 4096);                        \
      f32x4 o_ = __builtin_amdgcn_mfma_f32_16x16x32_bf16(v0, pfrag[0], OT[dt], 0, 0, 0);    \
      OT[dt] = __builtin_amdgcn_mfma_f32_16x16x32_bf16(v1, pfrag[1], o_, 0, 0, 0);          \
    }                                                                                       \
    __builtin_amdgcn_s_setprio(0);                                                          \
  }

  // ---- prologue: tiles 0,1 -> bufs 0,1 ----
  STG(0); STG(1);
  {
    const unsigned long long* mload = mp;
    mA = MRD(0); mB = MRD(1);
  }
  const unsigned long long* mload = mp + 2;
  __syncthreads();

  // 7 pairs of barrier intervals cover tiles 0..27 (4 tiles per pair).
  for (int i = 0; i < 7; ++i) {
    QKT(0, STa); QKT(1, STb);
    STG(2); STG(3);
    mnA = MRD(0); mnB = MRD(1);
    SM(STa, mA); PV(0);
    SM(STb, mB); PV(1);
    mA = mnA; mB = mnB;
    __syncthreads();
    QKT(2, STa); QKT(3, STb);
    STG(0); STG(1);
    mnA = MRD(2); mnB = MRD(3);
    SM(STa, mA); PV(2);
    SM(STb, mB); PV(3);
    mA = mnA; mB = mnB;
    mload += 4;
    __syncthreads();
  }
  // interval 14: tiles 28,29 (bufs 0,1); stage tiles 30,31 into bufs 2,3
  QKT(0, STa); QKT(1, STb);
  STG(2); STG(3);
  mnA = MRD(0); mnB = MRD(1);
  SM(STa, mA); PV(0);
  SM(STb, mB); PV(1);
  mA = mnA; mB = mnB;
  __syncthreads();
  // interval 15: tiles 30,31 (bufs 2,3); no staging
  QKT(2, STa); QKT(3, STb);
  SM(STa, mA); PV(2);
  SM(STb, mB); PV(3);
#undef MRD
#undef STG
#undef QKT
#undef SM
#undef PV

  // ---- epilogue: single l-reduction + store x[b][q][h*64+d] = O^T[d][q]/l ----
  {
    float l = rsacc;
    l += __shfl_xor(l, 16);
    l += __shfl_xor(l, 32);
    const float inv = (l > 0.f) ? 1.f / l : 0.f;
    const int q = q0 + w * 16 + lr;
#pragma unroll
    for (int dt = 0; dt < 4; ++dt) {
      uint2v o;
      o.x = cvtpk(OT[dt][0] * inv, OT[dt][1] * inv);
      o.y = cvtpk(OT[dt][2] * inv, OT[dt][3] * inv);
      *reinterpret_cast<uint2v*>(xg + ((size_t)(b * T_N + q)) * FDIM_N + h * 64 + dt * 16 +
                                 lg * 4) = o;
    }
  }
}

extern "C" void kernel_launch(void* const* d_in, const int* in_sizes, int n_in,
                              void* d_out, int out_size, void* d_ws, size_t ws_size,
                              hipStream_t stream) {
  const float* query = (const float*)d_in[0];
  const float* key = (const float*)d_in[1];
  const float* value = (const float*)d_in[2];
  const int* mask = (const int*)d_in[3];
  const float* Wq = (const float*)d_in[4];
  const float* bq = (const float*)d_in[5];
  const float* Wk = (const float*)d_in[6];
  const float* bk = (const float*)d_in[7];
  const float* Wv = (const float*)d_in[8];
  const float* bv = (const float*)d_in[9];
  const float* Wo = (const float*)d_in[10];
  const float* bo = (const float*)d_in[11];

  const size_t NE = (size_t)16384 * 512;
  const size_t WE = (size_t)512 * 512;
  unsigned short* qb_in = (unsigned short*)d_ws;  // bf16 inputs
  unsigned short* kb_in = qb_in + NE;
  unsigned short* vb_in = kb_in + NE;
  unsigned short* wqb = vb_in + NE;               // 4 weights bf16
  unsigned short* q_scr = wqb + 4 * WE;
  unsigned short* k_scr = q_scr + NE;
  unsigned short* vT_scr = k_scr + NE;
  unsigned long long* mbits = (unsigned long long*)(vT_scr + NE);
  unsigned short* x_scr = qb_in;  // alias: qb_in dead after gemm_q

  prep_k<<<3072, 256, 0, stream>>>(mask, Wq, Wk, Wv, Wo, query, key, value, wqb, qb_in, kb_in,
                                   vb_in, mbits);
  gemm_bt_k<0><<<512, 256, 0, stream>>>(qb_in, wqb + 0 * WE, bq, q_scr);
  gemm_bt_k<1><<<512, 256, 0, stream>>>(kb_in, wqb + 1 * WE, bk, k_scr);
  gemm_bt_k<2><<<512, 256, 0, stream>>>(vb_in, wqb + 2 * WE, bv, vT_scr);
  attn_k<<<1024, 512, 0, stream>>>(q_scr, k_scr, vT_scr, mbits, x_scr);
  gemm_bt_k<3><<<512, 256, 0, stream>>>(x_scr, wqb + 3 * WE, bo, (float*)d_out);
}